// Round 1
// baseline (175.948 us; speedup 1.0000x reference)
//
#include <hip/hip_runtime.h>

#define NTYPES 50
#define NCATS  20
#define EDIM   64
#define BATCH  4
#define SEQL   256

// ws layout (floats): [0]=ll_total, [1..4]=intsum per b, [5]=I0
#define WS_LL   0
#define WS_INT  1
#define WS_I0   5

__device__ __forceinline__ float softplusf(float x) {
    return (x > 0.f) ? x + log1pf(__expf(-x)) : log1pf(__expf(x));
}

__device__ __forceinline__ float waveReduceSum(float v) {
    #pragma unroll
    for (int off = 32; off > 0; off >>= 1) v += __shfl_down(v, off, 64);
    return v;
}

// One block per (b, i): lambda_i = intensity at times[i] with history s<i, at type types[i].
__global__ void ll_kernel(const float* __restrict__ times,
                          const int*   __restrict__ types,
                          const int*   __restrict__ cats,
                          const float* __restrict__ type_emb,
                          const float* __restrict__ cat_emb,
                          const float* __restrict__ amat,
                          const float* __restrict__ bmat,
                          const float* __restrict__ A,
                          const float* __restrict__ P,
                          const float* __restrict__ Bm,
                          const float* __restrict__ Q,
                          float* __restrict__ ws) {
    const int bi = blockIdx.x;
    const int b = bi / SEQL, i = bi % SEQL;
    const int tid  = threadIdx.x;
    const int lane = tid & 63;
    const int wave = tid >> 6;
    const int NW   = blockDim.x >> 6;

    const int t = types[b * SEQL + i];

    if (i == 0) {
        // empty-history branch: lam = sum_e softplus(type_emb[t,e]*a[t,e])
        if (wave == 0) {
            float x  = type_emb[t * EDIM + lane] * amat[t * EDIM + lane];
            float sp = softplusf(x);
            sp = waveReduceSum(sp);
            if (lane == 0) {
                float lam = sp;
                atomicAdd(&ws[WS_LL], logf(lam + 1e-16f) + lam);
            }
        }
        return;
    }

    const int c = cats[b * SEQL + (i - 1)];   // last_cat of the history
    const float te  = type_emb[t * EDIM + lane];
    const float ce  = cat_emb[c * EDIM + lane];
    const float t_i = times[b * SEQL + i];

    float acc = 0.f;
    for (int s = wave; s < i; s += NW) {
        const int   k  = types[b * SEQL + s];
        const int   cs = cats [b * SEQL + s];
        const float td = t_i - times[b * SEQL + s];
        const float f  = type_emb[k * EDIM + lane];
        const float g  = cat_emb [cs * EDIM + lane];
        const float Ak = A [(k  * NTYPES + t) * EDIM + lane];
        const float Pk = P [(k  * NTYPES + t) * EDIM + lane];
        const float Bk = Bm[(cs * NCATS  + c) * EDIM + lane];
        const float Qk = Q [(cs * NCATS  + c) * EDIM + lane];
        acc += te * Ak * f * __expf(-te * Pk * f * td)
             + te * ce * Bk * g * __expf(-ce * Qk * g * td);
    }
    if (wave == 0) acc += te * (amat[t * EDIM + lane] + bmat[c * EDIM + lane]);

    acc = waveReduceSum(acc);
    __shared__ float red[8];
    if (lane == 0) red[wave] = acc;
    __syncthreads();
    if (tid == 0) {
        float lam = 0.f;
        for (int w = 0; w < NW; ++w) lam += red[w];
        atomicAdd(&ws[WS_LL], logf(lam + 1e-16f) + lam);
    }
}

// One block per (b, t): type-channel part of sum_t full[t] at horizon T (full history).
__global__ void int_type_kernel(const float* __restrict__ times,
                                const int*   __restrict__ types,
                                const float* __restrict__ type_emb,
                                const float* __restrict__ A,
                                const float* __restrict__ P,
                                const int*   __restrict__ Tp,
                                float* __restrict__ ws) {
    const int bt = blockIdx.x;
    const int b = bt / NTYPES, t = bt % NTYPES;
    const int tid  = threadIdx.x;
    const int lane = tid & 63;
    const int wave = tid >> 6;
    const int NW   = blockDim.x >> 6;

    const float Tf = (float)Tp[0];
    const float te = type_emb[t * EDIM + lane];

    float acc = 0.f;
    for (int s = wave; s < SEQL; s += NW) {
        const int   k  = types[b * SEQL + s];
        const float td = Tf - times[b * SEQL + s];
        const float f  = type_emb[k * EDIM + lane];
        const float Ak = A[(k * NTYPES + t) * EDIM + lane];
        const float Pk = P[(k * NTYPES + t) * EDIM + lane];
        acc += te * Ak * f * __expf(-te * Pk * f * td);
    }
    acc = waveReduceSum(acc);
    __shared__ float red[8];
    if (lane == 0) red[wave] = acc;
    __syncthreads();
    if (tid == 0) {
        float tot = 0.f;
        for (int w = 0; w < NW; ++w) tot += red[w];
        atomicAdd(&ws[WS_INT + b], tot);
    }
}

// One block per b: category + base part of sum_t full[t] at horizon.
// sum_{t,e} te*(a+b[lc]+n[lc]) = sum_e [ TA_e + (b[lc,e]+n[lc,e]) * TS_e ]
__global__ void int_cat_kernel(const float* __restrict__ times,
                               const int*   __restrict__ cats,
                               const float* __restrict__ type_emb,
                               const float* __restrict__ cat_emb,
                               const float* __restrict__ amat,
                               const float* __restrict__ bmat,
                               const float* __restrict__ Bm,
                               const float* __restrict__ Q,
                               const int*   __restrict__ Tp,
                               float* __restrict__ ws) {
    const int b = blockIdx.x;
    const int tid  = threadIdx.x;
    const int lane = tid & 63;
    const int wave = tid >> 6;
    const int NW   = blockDim.x >> 6;

    const float Tf = (float)Tp[0];
    const int   lc = cats[b * SEQL + SEQL - 1];
    const float ce = cat_emb[lc * EDIM + lane];

    float nacc = 0.f;
    for (int s = wave; s < SEQL; s += NW) {
        const int   cs = cats[b * SEQL + s];
        const float td = Tf - times[b * SEQL + s];
        const float g  = cat_emb[cs * EDIM + lane];
        nacc += ce * Bm[(cs * NCATS + lc) * EDIM + lane]
                   * g * __expf(-ce * Q[(cs * NCATS + lc) * EDIM + lane] * g * td);
    }
    __shared__ float sn[4][EDIM];
    sn[wave][lane] = nacc;
    __syncthreads();
    if (wave == 0) {
        float n_e = 0.f;
        for (int w = 0; w < NW; ++w) n_e += sn[w][lane];
        float TA = 0.f, TS = 0.f;
        for (int t = 0; t < NTYPES; ++t) {
            const float tv = type_emb[t * EDIM + lane];
            TA += tv * amat[t * EDIM + lane];
            TS += tv;
        }
        float term = TA + (bmat[lc * EDIM + lane] + n_e) * TS;
        term = waveReduceSum(term);
        if (lane == 0) atomicAdd(&ws[WS_INT + b], term);
    }
}

// I0 = sum_{t,e} softplus(type_emb*a)  (one wave)
__global__ void i0_kernel(const float* __restrict__ type_emb,
                          const float* __restrict__ amat,
                          float* __restrict__ ws) {
    const int lane = threadIdx.x;
    float acc = 0.f;
    for (int t = 0; t < NTYPES; ++t)
        acc += softplusf(type_emb[t * EDIM + lane] * amat[t * EDIM + lane]);
    acc = waveReduceSum(acc);
    if (lane == 0) ws[WS_I0] = acc;
}

__global__ void finalize_kernel(const float* __restrict__ times,
                                const int*   __restrict__ Tp,
                                const float* __restrict__ ws,
                                float* __restrict__ out) {
    const float Tf = (float)Tp[0];
    float tot_int = 0.f;
    for (int b = 0; b < BATCH; ++b) {
        tot_int += ws[WS_INT + b] * (Tf - times[b * SEQL + SEQL - 1])
                 + ws[WS_I0] * times[b * SEQL + 0];
    }
    out[0] = -(ws[WS_LL] - tot_int);
}

extern "C" void kernel_launch(void* const* d_in, const int* in_sizes, int n_in,
                              void* d_out, int out_size, void* d_ws, size_t ws_size,
                              hipStream_t stream) {
    const float* times    = (const float*)d_in[0];
    const int*   types    = (const int*)  d_in[1];
    const int*   cats     = (const int*)  d_in[2];
    const int*   Tp       = (const int*)  d_in[3];
    const float* type_emb = (const float*)d_in[4];
    const float* cat_emb  = (const float*)d_in[5];
    const float* amat     = (const float*)d_in[6];
    const float* bmat     = (const float*)d_in[7];
    const float* A        = (const float*)d_in[8];
    const float* P        = (const float*)d_in[9];
    const float* Bm       = (const float*)d_in[10];
    const float* Q        = (const float*)d_in[11];
    float* out = (float*)d_out;
    float* ws  = (float*)d_ws;

    hipMemsetAsync(ws, 0, 6 * sizeof(float), stream);

    ll_kernel<<<BATCH * SEQL, 256, 0, stream>>>(times, types, cats, type_emb, cat_emb,
                                                amat, bmat, A, P, Bm, Q, ws);
    int_type_kernel<<<BATCH * NTYPES, 256, 0, stream>>>(times, types, type_emb, A, P, Tp, ws);
    int_cat_kernel<<<BATCH, 256, 0, stream>>>(times, cats, type_emb, cat_emb, amat, bmat,
                                              Bm, Q, Tp, ws);
    i0_kernel<<<1, 64, 0, stream>>>(type_emb, amat, ws);
    finalize_kernel<<<1, 1, 0, stream>>>(times, Tp, ws, out);
}

// Round 2
// 125.393 us; speedup vs baseline: 1.4032x; 1.4032x over previous
//
#include <hip/hip_runtime.h>

#define NTYPES 50
#define NCATS  20
#define EDIM   64
#define BATCH  4
#define SEQL   256

#define LL_BLOCKS    (BATCH * SEQL)     // 1024: one per (b,i)
#define IT_BLOCKS    (BATCH * NTYPES)   // 200 : one per (b,t) horizon type-channel
#define IC_BLOCKS    (BATCH)            // 4   : horizon category+base
#define I0_BLOCKS    1
#define TOTAL_BLOCKS (LL_BLOCKS + IT_BLOCKS + IC_BLOCKS + I0_BLOCKS)  // 1229

// ws floats: [0]=ll_total, [1..4]=int per b, [5]=I0, [6]=completion counter (as uint)

__device__ __forceinline__ float softplusf(float x) {
    return (x > 0.f) ? x + log1pf(__expf(-x)) : log1pf(__expf(x));
}

__device__ __forceinline__ float waveReduceSum(float v) {
    #pragma unroll
    for (int off = 32; off > 0; off >>= 1) v += __shfl_down(v, off, 64);
    return v;
}

__global__ __launch_bounds__(256) void hawkes_fused(
        const float* __restrict__ times,
        const int*   __restrict__ types,
        const int*   __restrict__ cats,
        const int*   __restrict__ Tp,
        const float* __restrict__ type_emb,
        const float* __restrict__ cat_emb,
        const float* __restrict__ amat,
        const float* __restrict__ bmat,
        const float* __restrict__ A,
        const float* __restrict__ P,
        const float* __restrict__ Bm,
        const float* __restrict__ Q,
        float* __restrict__ ws,
        float* __restrict__ out) {
    const int blk  = blockIdx.x;
    const int tid  = threadIdx.x;
    const int lane = tid & 63;
    const int wave = tid >> 6;

    __shared__ float red[4];
    __shared__ float sn[4][EDIM];

    if (blk < LL_BLOCKS) {
        // ---- log-likelihood term for event (b, i) ----
        const int b = blk / SEQL, i = blk % SEQL;
        const int t = types[b * SEQL + i];
        if (i == 0) {
            if (wave == 0) {
                float sp = softplusf(type_emb[t * EDIM + lane] * amat[t * EDIM + lane]);
                sp = waveReduceSum(sp);
                if (lane == 0) atomicAdd(&ws[0], logf(sp + 1e-16f) + sp);
            }
        } else {
            const int   c   = cats[b * SEQL + (i - 1)];
            const float te  = type_emb[t * EDIM + lane];
            const float ce  = cat_emb[c * EDIM + lane];
            const float t_i = times[b * SEQL + i];
            float acc = 0.f;
            for (int s = wave; s < i; s += 4) {
                const int   k  = types[b * SEQL + s];
                const int   cs = cats [b * SEQL + s];
                const float td = t_i - times[b * SEQL + s];
                const float f  = type_emb[k * EDIM + lane];
                const float g  = cat_emb [cs * EDIM + lane];
                const float Ak = A [(k  * NTYPES + t) * EDIM + lane];
                const float Pk = P [(k  * NTYPES + t) * EDIM + lane];
                const float Bk = Bm[(cs * NCATS  + c) * EDIM + lane];
                const float Qk = Q [(cs * NCATS  + c) * EDIM + lane];
                acc += te * Ak * f * __expf(-te * Pk * f * td)
                     + te * ce * Bk * g * __expf(-ce * Qk * g * td);
            }
            if (wave == 0) acc += te * (amat[t * EDIM + lane] + bmat[c * EDIM + lane]);
            acc = waveReduceSum(acc);
            if (lane == 0) red[wave] = acc;
            __syncthreads();
            if (tid == 0) {
                float lam = red[0] + red[1] + red[2] + red[3];
                atomicAdd(&ws[0], logf(lam + 1e-16f) + lam);
            }
        }
    } else if (blk < LL_BLOCKS + IT_BLOCKS) {
        // ---- horizon integral, type channel, (b, t) ----
        const int bt = blk - LL_BLOCKS;
        const int b = bt / NTYPES, t = bt % NTYPES;
        const float Tf = (float)Tp[0];
        const float te = type_emb[t * EDIM + lane];
        float acc = 0.f;
        for (int s = wave; s < SEQL; s += 4) {
            const int   k  = types[b * SEQL + s];
            const float td = Tf - times[b * SEQL + s];
            const float f  = type_emb[k * EDIM + lane];
            const float Ak = A[(k * NTYPES + t) * EDIM + lane];
            const float Pk = P[(k * NTYPES + t) * EDIM + lane];
            acc += te * Ak * f * __expf(-te * Pk * f * td);
        }
        acc = waveReduceSum(acc);
        if (lane == 0) red[wave] = acc;
        __syncthreads();
        if (tid == 0) atomicAdd(&ws[1 + b], red[0] + red[1] + red[2] + red[3]);
    } else if (blk < LL_BLOCKS + IT_BLOCKS + IC_BLOCKS) {
        // ---- horizon integral, category + base part, per b ----
        const int b = blk - LL_BLOCKS - IT_BLOCKS;
        const float Tf = (float)Tp[0];
        const int   lc = cats[b * SEQL + SEQL - 1];
        const float ce = cat_emb[lc * EDIM + lane];
        float nacc = 0.f;
        for (int s = wave; s < SEQL; s += 4) {
            const int   cs = cats[b * SEQL + s];
            const float td = Tf - times[b * SEQL + s];
            const float g  = cat_emb[cs * EDIM + lane];
            nacc += ce * Bm[(cs * NCATS + lc) * EDIM + lane]
                       * g * __expf(-ce * Q[(cs * NCATS + lc) * EDIM + lane] * g * td);
        }
        sn[wave][lane] = nacc;
        __syncthreads();
        if (wave == 0) {
            float n_e = sn[0][lane] + sn[1][lane] + sn[2][lane] + sn[3][lane];
            float TA = 0.f, TS = 0.f;
            for (int t = 0; t < NTYPES; ++t) {
                const float tv = type_emb[t * EDIM + lane];
                TA += tv * amat[t * EDIM + lane];
                TS += tv;
            }
            float term = TA + (bmat[lc * EDIM + lane] + n_e) * TS;
            term = waveReduceSum(term);
            if (lane == 0) atomicAdd(&ws[1 + b], term);
        }
    } else {
        // ---- I0 = sum softplus(type_emb*a), distributed over 4 waves ----
        float acc = 0.f;
        for (int t = wave; t < NTYPES; t += 4)
            acc += softplusf(type_emb[t * EDIM + lane] * amat[t * EDIM + lane]);
        acc = waveReduceSum(acc);
        if (lane == 0) red[wave] = acc;
        __syncthreads();
        if (tid == 0) atomicAdd(&ws[5], red[0] + red[1] + red[2] + red[3]);
    }

    // ---- last-block-done finalize (dispatch-order independent) ----
    if (tid == 0) {
        __threadfence();  // release our ws contributions
        unsigned int* counter = (unsigned int*)&ws[6];
        unsigned int old = atomicAdd(counter, 1u);
        if (old == TOTAL_BLOCKS - 1) {
            __threadfence();  // acquire
            // atomic reads -> L2-coherent view of all blocks' contributions
            float ll  = atomicAdd(&ws[0], 0.f);
            float i0  = atomicAdd(&ws[5], 0.f);
            float Tf  = (float)Tp[0];
            float tot = 0.f;
            for (int b = 0; b < BATCH; ++b) {
                float ib = atomicAdd(&ws[1 + b], 0.f);
                tot += ib * (Tf - times[b * SEQL + SEQL - 1]) + i0 * times[b * SEQL + 0];
            }
            out[0] = -(ll - tot);
        }
    }
}

extern "C" void kernel_launch(void* const* d_in, const int* in_sizes, int n_in,
                              void* d_out, int out_size, void* d_ws, size_t ws_size,
                              hipStream_t stream) {
    const float* times    = (const float*)d_in[0];
    const int*   types    = (const int*)  d_in[1];
    const int*   cats     = (const int*)  d_in[2];
    const int*   Tp       = (const int*)  d_in[3];
    const float* type_emb = (const float*)d_in[4];
    const float* cat_emb  = (const float*)d_in[5];
    const float* amat     = (const float*)d_in[6];
    const float* bmat     = (const float*)d_in[7];
    const float* A        = (const float*)d_in[8];
    const float* P        = (const float*)d_in[9];
    const float* Bm       = (const float*)d_in[10];
    const float* Q        = (const float*)d_in[11];
    float* out = (float*)d_out;
    float* ws  = (float*)d_ws;

    hipMemsetAsync(ws, 0, 32, stream);  // ws[0..6] zeroed (accumulators + counter)

    hawkes_fused<<<TOTAL_BLOCKS, 256, 0, stream>>>(times, types, cats, Tp,
                                                   type_emb, cat_emb, amat, bmat,
                                                   A, P, Bm, Q, ws, out);
}

// Round 3
// 120.548 us; speedup vs baseline: 1.4596x; 1.0402x over previous
//
#include <hip/hip_runtime.h>

#define NTYPES 50
#define NCATS  20
#define EDIM   64
#define BATCH  4
#define SEQL   256

#define LL_BLOCKS    (BATCH * SEQL)     // 1024: one per (b,i)
#define IT_BLOCKS    (BATCH * NTYPES)   // 200 : one per (b,t) horizon type-channel
#define IC_BLOCKS    (BATCH)            // 4   : horizon category+base
#define I0_BLOCKS    1
#define TOTAL_BLOCKS (LL_BLOCKS + IT_BLOCKS + IC_BLOCKS + I0_BLOCKS)  // 1229

// ws floats: [0]=ll_total, [1..4]=int per b, [5]=I0, [6]=completion counter (uint)

__device__ __forceinline__ float softplusf(float x) {
    return (x > 0.f) ? x + log1pf(__expf(-x)) : log1pf(__expf(x));
}

__device__ __forceinline__ float waveReduceSum(float v) {
    #pragma unroll
    for (int off = 32; off > 0; off >>= 1) v += __shfl_down(v, off, 64);
    return v;
}

__global__ __launch_bounds__(256) void hawkes_fused(
        const float* __restrict__ times,
        const int*   __restrict__ types,
        const int*   __restrict__ cats,
        const int*   __restrict__ Tp,
        const float* __restrict__ type_emb,
        const float* __restrict__ cat_emb,
        const float* __restrict__ amat,
        const float* __restrict__ bmat,
        const float* __restrict__ A,
        const float* __restrict__ P,
        const float* __restrict__ Bm,
        const float* __restrict__ Q,
        float* __restrict__ ws,
        float* __restrict__ out) {
    const int blk  = blockIdx.x;
    const int tid  = threadIdx.x;
    const int lane = tid & 63;
    const int wave = tid >> 6;

    // Premultiplied LDS tables: sA[k*64+e] = te_e * A[k,t,e] * f[k,e], etc.
    __shared__ float sA[NTYPES * EDIM];    // 12.8 KB
    __shared__ float sP[NTYPES * EDIM];    // 12.8 KB
    __shared__ float sB[NCATS * EDIM];     //  5.1 KB
    __shared__ float sQ[NCATS * EDIM];     //  5.1 KB
    __shared__ float stimes[SEQL];         //  1 KB
    __shared__ int   stypes[SEQL];         //  1 KB
    __shared__ int   scats [SEQL];         //  1 KB
    __shared__ float red[4];

    if (blk < LL_BLOCKS) {
        // ---- log-likelihood term for event (b, i) ----
        const int b = blk / SEQL, i = blk % SEQL;
        const int t = types[b * SEQL + i];
        if (i == 0) {
            if (wave == 0) {
                float sp = softplusf(type_emb[t * EDIM + lane] * amat[t * EDIM + lane]);
                sp = waveReduceSum(sp);
                if (lane == 0) atomicAdd(&ws[0], logf(sp + 1e-16f) + sp);
            }
        } else {
            const int   c   = cats[b * SEQL + (i - 1)];
            const float te  = type_emb[t * EDIM + lane];
            const float ce  = cat_emb[c * EDIM + lane];
            const float t_i = times[b * SEQL + i];
            // stage sequence
            for (int s = tid; s < SEQL; s += 256) {
                stimes[s] = times[b * SEQL + s];
                stypes[s] = types[b * SEQL + s];
                scats [s] = cats [b * SEQL + s];
            }
            // preload premultiplied tables (e = tid&63 is invariant per thread)
            for (int j = tid; j < NTYPES * EDIM; j += 256) {
                const int   k = j >> 6;
                const float f = type_emb[j];
                const int   g = (k * NTYPES + t) * EDIM + lane;
                sA[j] = te * A[g] * f;
                sP[j] = te * P[g] * f;
            }
            for (int j = tid; j < NCATS * EDIM; j += 256) {
                const int   cc = j >> 6;
                const float g  = cat_emb[j];
                const int   ix = (cc * NCATS + c) * EDIM + lane;
                sB[j] = ce * Bm[ix] * g;
                sQ[j] = ce * Q [ix] * g;
            }
            __syncthreads();
            float acc = 0.f;
            for (int s = wave; s < i; s += 4) {
                const int   ka = stypes[s] * EDIM + lane;
                const int   ca = scats [s] * EDIM + lane;
                const float td = t_i - stimes[s];
                acc += sA[ka] * __expf(-sP[ka] * td)
                     + sB[ca] * __expf(-sQ[ca] * td);
            }
            if (wave == 0) acc += te * (amat[t * EDIM + lane] + bmat[c * EDIM + lane]);
            acc = waveReduceSum(acc);
            if (lane == 0) red[wave] = acc;
            __syncthreads();
            if (tid == 0) {
                float lam = red[0] + red[1] + red[2] + red[3];
                atomicAdd(&ws[0], logf(lam + 1e-16f) + lam);
            }
        }
    } else if (blk < LL_BLOCKS + IT_BLOCKS) {
        // ---- horizon integral, type channel, (b, t) ----
        const int bt = blk - LL_BLOCKS;
        const int b = bt / NTYPES, t = bt % NTYPES;
        const float Tf = (float)Tp[0];
        const float te = type_emb[t * EDIM + lane];
        for (int s = tid; s < SEQL; s += 256) {
            stimes[s] = times[b * SEQL + s];
            stypes[s] = types[b * SEQL + s];
        }
        for (int j = tid; j < NTYPES * EDIM; j += 256) {
            const int   k = j >> 6;
            const float f = type_emb[j];
            const int   g = (k * NTYPES + t) * EDIM + lane;
            sA[j] = te * A[g] * f;
            sP[j] = te * P[g] * f;
        }
        __syncthreads();
        float acc = 0.f;
        for (int s = wave; s < SEQL; s += 4) {
            const int   ka = stypes[s] * EDIM + lane;
            const float td = Tf - stimes[s];
            acc += sA[ka] * __expf(-sP[ka] * td);
        }
        acc = waveReduceSum(acc);
        if (lane == 0) red[wave] = acc;
        __syncthreads();
        if (tid == 0) atomicAdd(&ws[1 + b], red[0] + red[1] + red[2] + red[3]);
    } else if (blk < LL_BLOCKS + IT_BLOCKS + IC_BLOCKS) {
        // ---- horizon integral, category + base part, per b ----
        const int b = blk - LL_BLOCKS - IT_BLOCKS;
        const float Tf = (float)Tp[0];
        const int   lc = cats[b * SEQL + SEQL - 1];
        const float ce = cat_emb[lc * EDIM + lane];
        for (int s = tid; s < SEQL; s += 256) {
            stimes[s] = times[b * SEQL + s];
            scats [s] = cats [b * SEQL + s];
        }
        for (int j = tid; j < NCATS * EDIM; j += 256) {
            const int   cc = j >> 6;
            const float g  = cat_emb[j];
            const int   ix = (cc * NCATS + lc) * EDIM + lane;
            sB[j] = ce * Bm[ix] * g;
            sQ[j] = ce * Q [ix] * g;
        }
        __syncthreads();
        float nacc = 0.f;
        for (int s = wave; s < SEQL; s += 4) {
            const int   ca = scats[s] * EDIM + lane;
            const float td = Tf - stimes[s];
            nacc += sB[ca] * __expf(-sQ[ca] * td);
        }
        // reduce n_e across waves (per-lane e), reusing sA as scratch
        sA[wave * EDIM + lane] = nacc;
        __syncthreads();
        if (wave == 0) {
            float n_e = sA[lane] + sA[EDIM + lane] + sA[2 * EDIM + lane] + sA[3 * EDIM + lane];
            float TA = 0.f, TS = 0.f;
            for (int t = 0; t < NTYPES; ++t) {
                const float tv = type_emb[t * EDIM + lane];
                TA += tv * amat[t * EDIM + lane];
                TS += tv;
            }
            float term = TA + (bmat[lc * EDIM + lane] + n_e) * TS;
            term = waveReduceSum(term);
            if (lane == 0) atomicAdd(&ws[1 + b], term);
        }
    } else {
        // ---- I0 = sum softplus(type_emb*a) ----
        float acc = 0.f;
        for (int t = wave; t < NTYPES; t += 4)
            acc += softplusf(type_emb[t * EDIM + lane] * amat[t * EDIM + lane]);
        acc = waveReduceSum(acc);
        if (lane == 0) red[wave] = acc;
        __syncthreads();
        if (tid == 0) atomicAdd(&ws[5], red[0] + red[1] + red[2] + red[3]);
    }

    // ---- last-block-done finalize (dispatch-order independent) ----
    if (tid == 0) {
        __threadfence();  // release our ws contributions
        unsigned int* counter = (unsigned int*)&ws[6];
        unsigned int old = atomicAdd(counter, 1u);
        if (old == TOTAL_BLOCKS - 1) {
            __threadfence();  // acquire
            float ll  = atomicAdd(&ws[0], 0.f);
            float i0  = atomicAdd(&ws[5], 0.f);
            float Tf  = (float)Tp[0];
            float tot = 0.f;
            for (int b = 0; b < BATCH; ++b) {
                float ib = atomicAdd(&ws[1 + b], 0.f);
                tot += ib * (Tf - times[b * SEQL + SEQL - 1]) + i0 * times[b * SEQL + 0];
            }
            out[0] = -(ll - tot);
        }
    }
}

extern "C" void kernel_launch(void* const* d_in, const int* in_sizes, int n_in,
                              void* d_out, int out_size, void* d_ws, size_t ws_size,
                              hipStream_t stream) {
    const float* times    = (const float*)d_in[0];
    const int*   types    = (const int*)  d_in[1];
    const int*   cats     = (const int*)  d_in[2];
    const int*   Tp       = (const int*)  d_in[3];
    const float* type_emb = (const float*)d_in[4];
    const float* cat_emb  = (const float*)d_in[5];
    const float* amat     = (const float*)d_in[6];
    const float* bmat     = (const float*)d_in[7];
    const float* A        = (const float*)d_in[8];
    const float* P        = (const float*)d_in[9];
    const float* Bm       = (const float*)d_in[10];
    const float* Q        = (const float*)d_in[11];
    float* out = (float*)d_out;
    float* ws  = (float*)d_ws;

    hipMemsetAsync(ws, 0, 32, stream);  // ws[0..6] zeroed (accumulators + counter)

    hawkes_fused<<<TOTAL_BLOCKS, 256, 0, stream>>>(times, types, cats, Tp,
                                                   type_emb, cat_emb, amat, bmat,
                                                   A, P, Bm, Q, ws, out);
}